// Round 3
// baseline (41.112 us; speedup 1.0000x reference)
//
#include <hip/hip_runtime.h>
#include <stdint.h>

#define WW 19
#define NP 361
#define NWD 6
#define M19 0x7FFFFu

// ---- compile-time bit masks (word form) -------------------------------------
constexpr uint64_t valid_word(int w) {
  uint64_t m = 0;
  for (int b = 0; b < 64; ++b) { int p = w * 64 + b; if (p < NP) m |= (1ull << b); }
  return m;
}
__device__ constexpr uint64_t VALIDM[NWD] = {
    valid_word(0), valid_word(1), valid_word(2),
    valid_word(3), valid_word(4), valid_word(5)};

// ---- row <-> word conversion ------------------------------------------------
__device__ __forceinline__ void words_to_rows(const uint64_t* W, uint32_t* R) {
#pragma unroll
  for (int r = 0; r < WW; ++r) {
    const int bit = WW * r;
    const int w = bit >> 6, sh = bit & 63;
    uint64_t x = W[w] >> sh;
    if (sh > 45) x |= W[w + 1] << (64 - sh);
    R[r] = (uint32_t)x & M19;
  }
}
__device__ __forceinline__ void rows_to_words(const uint32_t* R, uint64_t* W) {
#pragma unroll
  for (int i = 0; i < NWD; ++i) W[i] = 0;
#pragma unroll
  for (int r = 0; r < WW; ++r) {
    const int bit = WW * r;
    const int w = bit >> 6, sh = bit & 63;
    W[w] |= (uint64_t)R[r] << sh;
    if (sh > 45) W[w + 1] |= (uint64_t)R[r] >> (64 - sh);
  }
}

__device__ __forceinline__ uint32_t rev19(uint32_t x) { return __brev(x) >> 13; }

// Fill every run of m that contains a seed bit of g (requires g subset of m).
// Carry trick: (m+g)^m^g marks all bits that received a carry-in -> every run
// bit strictly above the lowest seed of its run; OR g covers the seeds; the
// bit-reversed pass covers [run bottom .. highest seed]. Union = full run.
__device__ __forceinline__ uint32_t runfill(uint32_t g, uint32_t m, uint32_t rm) {
  const uint32_t up = g | (m & ((m + g) ^ m ^ g));
  const uint32_t rg = rev19(g);
  const uint32_t dn = rg | (rm & ((rm + rg) ^ rm ^ rg));
  return up | rev19(dn);
}

// ================= K0: pack stones -> bitboards, zobrist hash ================
__global__ __launch_bounds__(256) void k0_pack_hash(
    const float* __restrict__ stones, const int* __restrict__ zob,
    const int* __restrict__ zturn, const int* __restrict__ phash,
    float* __restrict__ out, uint32_t* __restrict__ bbws, int B) {
  __shared__ uint32_t buf[4][24];
  const int wid = threadIdx.x >> 6;
  const int lane = threadIdx.x & 63;
  const int b = blockIdx.x * 4 + wid;
  if (b >= B) return;
  const float* sb = stones + (size_t)b * (2 * NP);
  int acc = 0;
#pragma unroll
  for (int i = 0; i < NWD; ++i) {
    const int p = i * 64 + lane;
    const bool inb = p < NP;
    const float bv = inb ? sb[p] : 0.0f;
    const float wv = inb ? sb[NP + p] : 0.0f;
    const bool bs = bv > 0.5f;
    const bool wsn = wv > 0.5f;
    const uint64_t bb = __ballot(bs);
    const uint64_t wb = __ballot(wsn);
    if (lane == 0) {
      buf[wid][2 * i + 0] = (uint32_t)bb;
      buf[wid][2 * i + 1] = (uint32_t)(bb >> 32);
      buf[wid][12 + 2 * i + 0] = (uint32_t)wb;
      buf[wid][12 + 2 * i + 1] = (uint32_t)(wb >> 32);
    }
    const int zb = inb ? zob[p] : 0;
    const int zw = inb ? zob[NP + p] : 0;
    acc ^= zb & (bs ? -1 : 0);
    acc ^= zw & (wsn ? -1 : 0);
  }
#pragma unroll
  for (int off = 32; off > 0; off >>= 1) acc ^= __shfl_xor(acc, off, 64);
  if (lane == 0) {
    const int h = phash[b] ^ acc ^ zturn[0] ^ zturn[1];
    out[3 * (size_t)B * NP + b] = (float)h;
  }
  if (lane < 24) bbws[(size_t)b * 24 + lane] = buf[wid][lane];
}

// ================= K1: one board per LANE — row-form algebra + scanline flood
__global__ __launch_bounds__(64, 1) void k1_flood(
    const uint32_t* __restrict__ bbws, const int* __restrict__ cur,
    const int* __restrict__ ko, uint32_t* __restrict__ plws, int B) {
  const int b = blockIdx.x * 64 + threadIdx.x;
  if (b >= B) return;

  // Load 12 u64 words (black, white bitboards).
  uint64_t bm[NWD], wm[NWD];
  const uint4* pb = (const uint4*)(bbws + (size_t)b * 24);
#pragma unroll
  for (int j = 0; j < 6; ++j) {
    const uint4 v = pb[j];
    const uint64_t lo = (uint64_t)v.x | ((uint64_t)v.y << 32);
    const uint64_t hi = (uint64_t)v.z | ((uint64_t)v.w << 32);
    if (j < 3) { bm[2 * j] = lo; bm[2 * j + 1] = hi; }
    else       { wm[2 * (j - 3)] = lo; wm[2 * (j - 3) + 1] = hi; }
  }

  const int cp = cur[b];
  uint64_t oppw[NWD], empw[NWD];
#pragma unroll
  for (int i = 0; i < NWD; ++i) {
    oppw[i] = (cp == 0) ? wm[i] : bm[i];
    empw[i] = ~(bm[i] | wm[i]) & VALIDM[i];
  }

  // Convert to row form.
  uint32_t m[WW], e[WW];
  words_to_rows(oppw, m);
  words_to_rows(empw, e);

  // Per-row liberty bits (count of empty orthogonal neighbors, 0..4 as 3-bit).
  uint32_t L0[WW], L1[WW], L2[WW], leg[WW], vul[WW];
#pragma unroll
  for (int r = 0; r < WW; ++r) {
    const uint32_t u = (r > 0) ? e[r - 1] : 0u;
    const uint32_t d = (r < WW - 1) ? e[r + 1] : 0u;
    const uint32_t l = (e[r] << 1) & M19;
    const uint32_t rr = e[r] >> 1;
    const uint32_t s1 = u ^ d, c1 = u & d;
    const uint32_t s2 = l ^ rr, c2 = l & rr;
    const uint32_t cc = s1 & s2;
    L0[r] = s1 ^ s2;
    L1[r] = c1 ^ c2 ^ cc;
    L2[r] = (c1 & c2) | (cc & (c1 | c2));
    leg[r] = e[r] & (u | d | l | rr);
    vul[r] = m[r] & L0[r] & ~L1[r];  // liberty count == 1
  }

  // Capture moves: empty adjacent to a vulnerable stone.
#pragma unroll
  for (int r = 0; r < WW; ++r) {
    const uint32_t nb = ((r > 0) ? vul[r - 1] : 0u) |
                        ((r < WW - 1) ? vul[r + 1] : 0u) |
                        ((vul[r] << 1) & M19) | (vul[r] >> 1);
    leg[r] |= e[r] & nb;
  }

  // Ko point (row form: trivial single-bit clear).
  const int2 kk = ((const int2*)ko)[b];
  if (kk.x >= 0) leg[kk.x] &= ~(1u << kk.y);

  // Store L0,L1,L2,legal planes (word form) now to release registers.
  uint4* pw = (uint4*)(plws + (size_t)b * 60);
  {
    uint64_t W[NWD];
    uint4 v;
    rows_to_words(L0, W);
#pragma unroll
    for (int j = 0; j < 3; ++j) {
      v.x = (uint32_t)W[2 * j];     v.y = (uint32_t)(W[2 * j] >> 32);
      v.z = (uint32_t)W[2 * j + 1]; v.w = (uint32_t)(W[2 * j + 1] >> 32);
      pw[j] = v;
    }
    rows_to_words(L1, W);
#pragma unroll
    for (int j = 0; j < 3; ++j) {
      v.x = (uint32_t)W[2 * j];     v.y = (uint32_t)(W[2 * j] >> 32);
      v.z = (uint32_t)W[2 * j + 1]; v.w = (uint32_t)(W[2 * j + 1] >> 32);
      pw[3 + j] = v;
    }
    rows_to_words(L2, W);
#pragma unroll
    for (int j = 0; j < 3; ++j) {
      v.x = (uint32_t)W[2 * j];     v.y = (uint32_t)(W[2 * j] >> 32);
      v.z = (uint32_t)W[2 * j + 1]; v.w = (uint32_t)(W[2 * j + 1] >> 32);
      pw[6 + j] = v;
    }
    rows_to_words(leg, W);
#pragma unroll
    for (int j = 0; j < 3; ++j) {
      v.x = (uint32_t)W[2 * j];     v.y = (uint32_t)(W[2 * j] >> 32);
      v.z = (uint32_t)W[2 * j + 1]; v.w = (uint32_t)(W[2 * j + 1] >> 32);
      pw[9 + j] = v;
    }
  }

  // Scanline flood: g = components of m (opponent) containing vul seeds.
  uint32_t g[WW], rm[WW];
#pragma unroll
  for (int r = 0; r < WW; ++r) {
    rm[r] = rev19(m[r]);
    g[r] = runfill(vul[r], m[r], rm[r]);
  }
  for (int it = 0; it < 90; ++it) {
    uint32_t ex[WW], any = 0;
#pragma unroll
    for (int r = 0; r < WW; ++r) {
      const uint32_t nb = ((r > 0) ? g[r - 1] : 0u) | ((r < WW - 1) ? g[r + 1] : 0u);
      ex[r] = nb & m[r] & ~g[r];
      any |= ex[r];
    }
    if (!__any(any != 0u)) break;
#pragma unroll
    for (int r = 0; r < WW; ++r) g[r] = runfill(g[r] | ex[r], m[r], rm[r]);
  }

  // Store groups plane.
  {
    uint64_t W[NWD];
    uint4 v;
    rows_to_words(g, W);
#pragma unroll
    for (int j = 0; j < 3; ++j) {
      v.x = (uint32_t)W[2 * j];     v.y = (uint32_t)(W[2 * j] >> 32);
      v.z = (uint32_t)W[2 * j + 1]; v.w = (uint32_t)(W[2 * j + 1] >> 32);
      pw[12 + j] = v;
    }
  }
}

// ================= K2: expand bitplanes -> float outputs =====================
__global__ __launch_bounds__(256) void k2_expand(
    const uint32_t* __restrict__ plws, float* __restrict__ out, int B) {
  const int wid = threadIdx.x >> 6;
  const int lane = threadIdx.x & 63;
  const int b = blockIdx.x * 4 + wid;
  if (b >= B) return;
  const size_t NB = (size_t)B * NP;
  const uint64_t* rec = (const uint64_t*)(plws + (size_t)b * 60);
  float* o0 = out + (size_t)b * NP;
#pragma unroll
  for (int i = 0; i < NWD; ++i) {
    const int p = i * 64 + lane;
    if (p < NP) {
      const uint32_t l0 = (uint32_t)(rec[i] >> lane) & 1u;
      const uint32_t l1 = (uint32_t)(rec[6 + i] >> lane) & 1u;
      const uint32_t l2 = (uint32_t)(rec[12 + i] >> lane) & 1u;
      o0[p] = (float)(l0 + 2u * l1 + 4u * l2);
      o0[NB + p] = (float)((uint32_t)(rec[18 + i] >> lane) & 1u);
      o0[2 * NB + p] = (float)((uint32_t)(rec[24 + i] >> lane) & 1u);
    }
  }
}

// ================= fallback: single kernel (if ws too small) =================
__device__ __forceinline__ uint64_t dil_u(const uint64_t* m, int i) {
  return (m[i] << WW) | (i > 0 ? m[i - 1] >> (64 - WW) : 0ull);
}
__device__ __forceinline__ uint64_t dil_d(const uint64_t* m, int i) {
  return (m[i] >> WW) | (i < 5 ? m[i + 1] << (64 - WW) : 0ull);
}
constexpr uint64_t notcol_word(int w, int col) {
  uint64_t m = 0;
  for (int b = 0; b < 64; ++b) {
    int p = w * 64 + b;
    if (p < NP && (p % WW) != col) m |= (1ull << b);
  }
  return m;
}
__device__ constexpr uint64_t NC0[NWD] = {
    notcol_word(0, 0), notcol_word(1, 0), notcol_word(2, 0),
    notcol_word(3, 0), notcol_word(4, 0), notcol_word(5, 0)};
__device__ constexpr uint64_t NC18[NWD] = {
    notcol_word(0, 18), notcol_word(1, 18), notcol_word(2, 18),
    notcol_word(3, 18), notcol_word(4, 18), notcol_word(5, 18)};
__device__ __forceinline__ uint64_t dil_l(const uint64_t* m, int i) {
  return ((m[i] << 1) | (i > 0 ? m[i - 1] >> 63 : 0ull)) & NC0[i];
}
__device__ __forceinline__ uint64_t dil_r(const uint64_t* m, int i) {
  return ((m[i] >> 1) | (i < 5 ? m[i + 1] << 63 : 0ull)) & NC18[i];
}
__device__ __forceinline__ uint64_t dil4(const uint64_t* m, int i) {
  return dil_u(m, i) | dil_d(m, i) | dil_l(m, i) | dil_r(m, i);
}

__global__ __launch_bounds__(256) void go_fallback(
    const float* __restrict__ stones, const int* __restrict__ cur,
    const int* __restrict__ ko, const int* __restrict__ zob,
    const int* __restrict__ zturn, const int* __restrict__ phash,
    float* __restrict__ out, int B) {
  const int wid = threadIdx.x >> 6;
  const int lane = threadIdx.x & 63;
  const int b = blockIdx.x * 4 + wid;
  if (b >= B) return;
  const size_t NB = (size_t)B * NP;
  const float* sb = stones + (size_t)b * (2 * NP);
  uint64_t bm[NWD], wm[NWD];
  int acc = 0;
#pragma unroll
  for (int i = 0; i < NWD; ++i) {
    const int p = i * 64 + lane;
    const bool inb = p < NP;
    const float bv = inb ? sb[p] : 0.0f;
    const float wv = inb ? sb[NP + p] : 0.0f;
    const bool bs = bv > 0.5f, wsn = wv > 0.5f;
    bm[i] = __ballot(bs);
    wm[i] = __ballot(wsn);
    const int zb = inb ? zob[p] : 0;
    const int zw = inb ? zob[NP + p] : 0;
    acc ^= zb & (bs ? -1 : 0);
    acc ^= zw & (wsn ? -1 : 0);
  }
  const int cp = cur[b];
  uint64_t opp[NWD], emp[NWD];
#pragma unroll
  for (int i = 0; i < NWD; ++i) {
    opp[i] = (cp == 0) ? wm[i] : bm[i];
    emp[i] = ~(bm[i] | wm[i]) & VALIDM[i];
  }
  uint64_t ue[NWD], de[NWD], le[NWD], re[NWD], vul[NWD], legal[NWD];
#pragma unroll
  for (int i = 0; i < NWD; ++i) {
    ue[i] = dil_u(emp, i); de[i] = dil_d(emp, i);
    le[i] = dil_l(emp, i); re[i] = dil_r(emp, i);
  }
#pragma unroll
  for (int i = 0; i < NWD; ++i) {
    const uint64_t s1 = ue[i] ^ de[i], c1 = ue[i] & de[i];
    const uint64_t s2 = le[i] ^ re[i], c2 = le[i] & re[i];
    const uint64_t one = (s1 ^ s2) & ~(c1 | c2 | (s1 & s2));
    vul[i] = opp[i] & one;
    legal[i] = emp[i] & (ue[i] | de[i] | le[i] | re[i]);
  }
#pragma unroll
  for (int i = 0; i < NWD; ++i) legal[i] |= emp[i] & dil4(vul, i);
  const int kr = ko[2 * b], kc = ko[2 * b + 1];
  const int kp = (kr >= 0) ? (kr * WW + kc) : -1;
#pragma unroll
  for (int i = 0; i < NWD; ++i) {
    const uint64_t bit =
        ((unsigned)(kp - i * 64) < 64u) ? (1ull << (kp - i * 64)) : 0ull;
    legal[i] &= ~bit;
  }
  uint64_t g[NWD];
#pragma unroll
  for (int i = 0; i < NWD; ++i) g[i] = vul[i];
  for (int it = 0; it < 90; ++it) {
    uint64_t ex[NWD], any = 0;
#pragma unroll
    for (int i = 0; i < NWD; ++i) {
      ex[i] = dil4(g, i) & opp[i] & ~g[i];
      any |= ex[i];
    }
    if (any == 0) break;
#pragma unroll
    for (int i = 0; i < NWD; ++i) g[i] |= ex[i];
  }
#pragma unroll
  for (int i = 0; i < NWD; ++i) {
    const int p = i * 64 + lane;
    if (p < NP) {
      const uint32_t l1 = (uint32_t)(ue[i] >> lane) & 1u;
      const uint32_t l2 = (uint32_t)(de[i] >> lane) & 1u;
      const uint32_t l3 = (uint32_t)(le[i] >> lane) & 1u;
      const uint32_t l4 = (uint32_t)(re[i] >> lane) & 1u;
      const size_t o = (size_t)b * NP + p;
      out[o] = (float)(l1 + l2 + l3 + l4);
      out[NB + o] = (float)((uint32_t)(legal[i] >> lane) & 1u);
      out[2 * NB + o] = (float)((uint32_t)(g[i] >> lane) & 1u);
    }
  }
#pragma unroll
  for (int off = 32; off > 0; off >>= 1) acc ^= __shfl_xor(acc, off, 64);
  if (lane == 0) {
    const int h = phash[b] ^ acc ^ zturn[0] ^ zturn[1];
    out[3 * NB + b] = (float)h;
  }
}

extern "C" void kernel_launch(void* const* d_in, const int* in_sizes, int n_in,
                              void* d_out, int out_size, void* d_ws,
                              size_t ws_size, hipStream_t stream) {
  const float* stones = (const float*)d_in[0];
  const int* cur = (const int*)d_in[1];
  const int* ko = (const int*)d_in[2];
  const int* zob = (const int*)d_in[3];
  const int* zturn = (const int*)d_in[4];
  const int* phash = (const int*)d_in[5];
  float* out = (float*)d_out;

  const int B = in_sizes[0] / (2 * NP);
  const size_t need = (size_t)B * (96 + 240);  // bitboards + planes

  if (ws_size >= need) {
    uint32_t* bbws = (uint32_t*)d_ws;
    uint32_t* plws = bbws + (size_t)B * 24;
    k0_pack_hash<<<(B + 3) / 4, 256, 0, stream>>>(stones, zob, zturn, phash,
                                                  out, bbws, B);
    k1_flood<<<(B + 63) / 64, 64, 0, stream>>>(bbws, cur, ko, plws, B);
    k2_expand<<<(B + 3) / 4, 256, 0, stream>>>(plws, out, B);
  } else {
    go_fallback<<<(B + 3) / 4, 256, 0, stream>>>(stones, cur, ko, zob, zturn,
                                                 phash, out, B);
  }
}

// Round 4
// 33.484 us; speedup vs baseline: 1.2278x; 1.2278x over previous
//
#include <hip/hip_runtime.h>
#include <stdint.h>

#define WW 19
#define NP 361
#define M19 0x7FFFFu
#define BPB 32   // boards per block
#define TPB 512  // 8 waves
#define BBSTR 25 // u32 stride for packed bitboards in LDS (coprime with 32)
#define PLSTR 97 // u32 stride for row-planes in LDS (97 % 32 == 1)

__device__ __forceinline__ uint32_t rev19(uint32_t x) { return __brev(x) >> 13; }

// Fill every run of m containing a seed of g (g subset of m).
__device__ __forceinline__ uint32_t runfill(uint32_t g, uint32_t m, uint32_t rm) {
  const uint32_t up = g | (m & ((m + g) ^ m ^ g));
  const uint32_t rg = rev19(g);
  const uint32_t dn = rg | (rm & ((rm + rg) ^ rm ^ rg));
  return up | rev19(dn);
}

__global__ __launch_bounds__(TPB, 4) void go_fused(
    const float* __restrict__ stones, const int* __restrict__ cur,
    const int* __restrict__ ko, const int* __restrict__ zob,
    const int* __restrict__ zturn, const int* __restrict__ phash,
    float* __restrict__ out, int B) {
  __shared__ uint32_t bbuf[BPB * BBSTR];
  __shared__ uint32_t pl[BPB * PLSTR];

  const int wid = threadIdx.x >> 6;
  const int lane = threadIdx.x & 63;
  const size_t NB = (size_t)B * NP;

  // Zobrist tables: uniform, L2-cached; preload once per thread.
  int zb[6], zw[6];
#pragma unroll
  for (int i = 0; i < 6; ++i) {
    const int p = i * 64 + lane;
    zb[i] = (p < NP) ? zob[p] : 0;
    zw[i] = (p < NP) ? zob[NP + p] : 0;
  }
  const int zt = zturn[0] ^ zturn[1];

  // ---------------- phase 1: pack stones -> LDS bitboards, zobrist hash -----
#pragma unroll
  for (int k = 0; k < 4; ++k) {
    const int lb = wid * 4 + k;
    const int b = blockIdx.x * BPB + lb;
    if (b < B) {
      const float* sb = stones + (size_t)b * (2 * NP);
      int acc = 0;
#pragma unroll
      for (int i = 0; i < 6; ++i) {
        const int p = i * 64 + lane;
        const bool inb = p < NP;
        const float bv = inb ? sb[p] : 0.0f;
        const float wv = inb ? sb[NP + p] : 0.0f;
        const bool bs = bv > 0.5f, wsn = wv > 0.5f;
        const uint64_t bbm = __ballot(bs);
        const uint64_t wbm = __ballot(wsn);
        if (lane < 4) {
          const uint64_t src = (lane < 2) ? bbm : wbm;
          const uint32_t vv = (lane & 1) ? (uint32_t)(src >> 32) : (uint32_t)src;
          bbuf[lb * BBSTR + i * 4 + lane] = vv;
        }
        acc ^= zb[i] & (bs ? -1 : 0);
        acc ^= zw[i] & (wsn ? -1 : 0);
      }
#pragma unroll
      for (int off = 32; off > 0; off >>= 1) acc ^= __shfl_xor(acc, off, 64);
      if (lane == 0) out[3 * NB + b] = (float)(phash[b] ^ acc ^ zt);
    }
  }
  __syncthreads();

  // ---------------- phase 2: one board per lane (threads 0..31) -------------
  if (threadIdx.x < BPB) {
    const int lb = threadIdx.x;
    const int b = blockIdx.x * BPB + lb;
    if (b < B) {
      // Reconstruct 6-word bitboards from LDS (conflict-free: stride 25).
      uint64_t bmw[6], wmw[6];
#pragma unroll
      for (int i = 0; i < 6; ++i) {
        const uint32_t* q = &bbuf[lb * BBSTR + 4 * i];
        bmw[i] = (uint64_t)q[0] | ((uint64_t)q[1] << 32);
        wmw[i] = (uint64_t)q[2] | ((uint64_t)q[3] << 32);
      }
      const int cp = cur[b];
      // Rows: m = opponent, e = empty.
      uint32_t m[WW], e[WW];
#pragma unroll
      for (int r = 0; r < WW; ++r) {
        const int bit = WW * r;
        const int w = bit >> 6, sh = bit & 63;
        uint64_t xb = bmw[w] >> sh;
        uint64_t xw = wmw[w] >> sh;
        if (sh > 45) { xb |= bmw[w + 1] << (64 - sh); xw |= wmw[w + 1] << (64 - sh); }
        const uint32_t br = (uint32_t)xb & M19;
        const uint32_t wr = (uint32_t)xw & M19;
        m[r] = (cp == 0) ? wr : br;
        e[r] = ~(br | wr) & M19;
      }

      uint32_t* pb = &pl[lb * PLSTR];
      // Liberty bit-planes L0,L1,L2 (stored straight to LDS) + vulnerable.
      uint32_t vul[WW];
#pragma unroll
      for (int r = 0; r < WW; ++r) {
        const uint32_t u = (r > 0) ? e[r - 1] : 0u;
        const uint32_t d = (r < WW - 1) ? e[r + 1] : 0u;
        const uint32_t l = (e[r] << 1) & M19;
        const uint32_t rr = e[r] >> 1;
        const uint32_t s1 = u ^ d, c1 = u & d;
        const uint32_t s2 = l ^ rr, c2 = l & rr;
        const uint32_t cc = s1 & s2;
        const uint32_t L0 = s1 ^ s2;
        const uint32_t L1 = c1 ^ c2 ^ cc;
        pb[r] = L0;
        pb[19 + r] = L1;
        pb[38 + r] = (c1 & c2) | (cc & (c1 | c2));
        vul[r] = m[r] & L0 & ~L1;  // liberty count == 1
      }

      // legal = empty&(libs>0) | empty&nb(vul); minus ko point.
      const int2 kk = ((const int2*)ko)[b];
#pragma unroll
      for (int r = 0; r < WW; ++r) {
        const uint32_t u = (r > 0) ? e[r - 1] : 0u;
        const uint32_t d = (r < WW - 1) ? e[r + 1] : 0u;
        const uint32_t nbv = ((r > 0) ? vul[r - 1] : 0u) |
                             ((r < WW - 1) ? vul[r + 1] : 0u) |
                             ((vul[r] << 1) & M19) | (vul[r] >> 1);
        uint32_t leg = e[r] & (u | d | ((e[r] << 1) & M19) | (e[r] >> 1));
        leg |= e[r] & nbv;
        if (kk.x == r) leg &= ~(1u << kk.y);
        pb[57 + r] = leg;
      }

      // Scanline flood of vul seeds within m.
      uint32_t g[WW], rm[WW];
#pragma unroll
      for (int r = 0; r < WW; ++r) {
        rm[r] = rev19(m[r]);
        g[r] = runfill(vul[r], m[r], rm[r]);
      }
      for (int it = 0; it < 90; ++it) {
        uint32_t ex[WW], any = 0;
#pragma unroll
        for (int r = 0; r < WW; ++r) {
          const uint32_t nb = ((r > 0) ? g[r - 1] : 0u) |
                              ((r < WW - 1) ? g[r + 1] : 0u);
          ex[r] = nb & m[r] & ~g[r];
          any |= ex[r];
        }
        if (!__any(any != 0u)) break;
#pragma unroll
        for (int r = 0; r < WW; ++r) g[r] = runfill(g[r] | ex[r], m[r], rm[r]);
      }
#pragma unroll
      for (int r = 0; r < WW; ++r) pb[76 + r] = g[r];
    }
  }
  __syncthreads();

  // ---------------- phase 3: expand LDS row-planes -> float outputs ---------
#pragma unroll
  for (int k = 0; k < 4; ++k) {
    const int lb = wid * 4 + k;
    const int b = blockIdx.x * BPB + lb;
    if (b < B) {
      float* o0 = out + (size_t)b * NP;
      const uint32_t* pb = &pl[lb * PLSTR];
#pragma unroll
      for (int i = 0; i < 6; ++i) {
        const int p = i * 64 + lane;
        if (p < NP) {
          const int r = (27 * p) >> 9;   // p/19 for p<512
          const int c = p - 19 * r;
          const uint32_t l0 = (pb[r] >> c) & 1u;
          const uint32_t l1 = (pb[19 + r] >> c) & 1u;
          const uint32_t l2 = (pb[38 + r] >> c) & 1u;
          o0[p] = (float)(l0 + 2u * l1 + 4u * l2);
          o0[NB + p] = (float)((pb[57 + r] >> c) & 1u);
          o0[2 * NB + p] = (float)((pb[76 + r] >> c) & 1u);
        }
      }
    }
  }
}

extern "C" void kernel_launch(void* const* d_in, const int* in_sizes, int n_in,
                              void* d_out, int out_size, void* d_ws,
                              size_t ws_size, hipStream_t stream) {
  const float* stones = (const float*)d_in[0];
  const int* cur = (const int*)d_in[1];
  const int* ko = (const int*)d_in[2];
  const int* zob = (const int*)d_in[3];
  const int* zturn = (const int*)d_in[4];
  const int* phash = (const int*)d_in[5];
  float* out = (float*)d_out;

  const int B = in_sizes[0] / (2 * NP);
  const int blocks = (B + BPB - 1) / BPB;
  go_fused<<<blocks, TPB, 0, stream>>>(stones, cur, ko, zob, zturn, phash, out,
                                       B);
}

// Round 5
// 32.745 us; speedup vs baseline: 1.2555x; 1.0226x over previous
//
#include <hip/hip_runtime.h>
#include <stdint.h>

#define WW 19
#define NP 361
#define M19 0x7FFFFu
#define BPB 16   // boards per block
#define TPB 256  // 4 waves
#define BBSTR 25 // u32 stride for packed bitboards in LDS
#define PLSTR 97 // u32 stride for row-planes in LDS

__device__ __forceinline__ uint32_t rev19(uint32_t x) { return __brev(x) >> 13; }

// Fill every horizontal run of m containing a seed of g (g subset of m).
__device__ __forceinline__ uint32_t runfill(uint32_t g, uint32_t m) {
  const uint32_t up = g | (m & ((m + g) ^ m ^ g));
  const uint32_t rm = rev19(m);
  const uint32_t rg = rev19(g);
  const uint32_t dn = rg | (rm & ((rm + rg) ^ rm ^ rg));
  return up | rev19(dn);
}

__global__ __launch_bounds__(TPB, 2) void go_fused(
    const float* __restrict__ stones, const int* __restrict__ cur,
    const int* __restrict__ ko, const int* __restrict__ zob,
    const int* __restrict__ zturn, const int* __restrict__ phash,
    float* __restrict__ out, int B) {
  __shared__ uint32_t bbuf[BPB * BBSTR];
  __shared__ uint32_t pl[BPB * PLSTR];

  const int wid = threadIdx.x >> 6;
  const int lane = threadIdx.x & 63;
  const int b0 = blockIdx.x * BPB;
  const size_t NB = (size_t)B * NP;

  // Zobrist tables: uniform across blocks, L1/L2-cached.
  int zb[6], zw[6];
#pragma unroll
  for (int i = 0; i < 6; ++i) {
    const int p = i * 64 + lane;
    zb[i] = (p < NP) ? zob[p] : 0;
    zw[i] = (p < NP) ? zob[NP + p] : 0;
  }
  const int zt = zturn[0] ^ zturn[1];

  // ---------------- phase 1: pack stones -> LDS bitboards, zobrist hash -----
  int acc[4];
#pragma unroll
  for (int k = 0; k < 4; ++k) {
    const int lb = wid * 4 + k;
    const int b = b0 + lb;
    acc[k] = 0;
    if (b < B) {
      const float* sb = stones + (size_t)b * (2 * NP);
#pragma unroll
      for (int i = 0; i < 6; ++i) {
        const int p = i * 64 + lane;
        const bool inb = p < NP;
        const float bv = inb ? sb[p] : 0.0f;
        const float wv = inb ? sb[NP + p] : 0.0f;
        const bool bs = bv > 0.5f, wsn = wv > 0.5f;
        const uint64_t bbm = __ballot(bs);
        const uint64_t wbm = __ballot(wsn);
        if (lane < 4) {
          const uint64_t src = (lane < 2) ? bbm : wbm;
          const uint32_t vv = (lane & 1) ? (uint32_t)(src >> 32) : (uint32_t)src;
          bbuf[lb * BBSTR + i * 4 + lane] = vv;
        }
        acc[k] ^= zb[i] & (bs ? -1 : 0);
        acc[k] ^= zw[i] & (wsn ? -1 : 0);
      }
    }
  }
  // 4 independent shfl-xor chains (latency overlapped).
#pragma unroll
  for (int off = 32; off > 0; off >>= 1) {
#pragma unroll
    for (int k = 0; k < 4; ++k) acc[k] ^= __shfl_xor(acc[k], off, 64);
  }
  if (lane == 0) {
#pragma unroll
    for (int k = 0; k < 4; ++k) {
      const int b = b0 + wid * 4 + k;
      if (b < B) out[3 * NB + b] = (float)(phash[b] ^ acc[k] ^ zt);
    }
  }
  __syncthreads();

  // ---------------- phase 2: one board per lane (threads 0..15) -------------
  if (threadIdx.x < BPB) {
    const int lb = threadIdx.x;
    const int b = b0 + lb;
    if (b < B) {
      uint64_t bmw[6], wmw[6];
#pragma unroll
      for (int i = 0; i < 6; ++i) {
        const uint32_t* q = &bbuf[lb * BBSTR + 4 * i];
        bmw[i] = (uint64_t)q[0] | ((uint64_t)q[1] << 32);
        wmw[i] = (uint64_t)q[2] | ((uint64_t)q[3] << 32);
      }
      const int cp = cur[b];
      uint32_t m[WW], e[WW];
#pragma unroll
      for (int r = 0; r < WW; ++r) {
        const int bit = WW * r;
        const int w = bit >> 6, sh = bit & 63;
        uint64_t xb = bmw[w] >> sh;
        uint64_t xw = wmw[w] >> sh;
        if (sh > 45) { xb |= bmw[w + 1] << (64 - sh); xw |= wmw[w + 1] << (64 - sh); }
        const uint32_t br = (uint32_t)xb & M19;
        const uint32_t wr = (uint32_t)xw & M19;
        m[r] = (cp == 0) ? wr : br;
        e[r] = ~(br | wr) & M19;
      }

      uint32_t* pb = &pl[lb * PLSTR];
      uint32_t vul[WW];
#pragma unroll
      for (int r = 0; r < WW; ++r) {
        const uint32_t u = (r > 0) ? e[r - 1] : 0u;
        const uint32_t d = (r < WW - 1) ? e[r + 1] : 0u;
        const uint32_t l = (e[r] << 1) & M19;
        const uint32_t rr = e[r] >> 1;
        const uint32_t s1 = u ^ d, c1 = u & d;
        const uint32_t s2 = l ^ rr, c2 = l & rr;
        const uint32_t cc = s1 & s2;
        const uint32_t L0 = s1 ^ s2;
        const uint32_t L1 = c1 ^ c2 ^ cc;
        pb[r] = L0;
        pb[19 + r] = L1;
        pb[38 + r] = (c1 & c2) | (cc & (c1 | c2));
        vul[r] = m[r] & L0 & ~L1;  // liberty count == 1
      }

      const int2 kk = ((const int2*)ko)[b];
#pragma unroll
      for (int r = 0; r < WW; ++r) {
        const uint32_t u = (r > 0) ? e[r - 1] : 0u;
        const uint32_t d = (r < WW - 1) ? e[r + 1] : 0u;
        const uint32_t nbv = ((r > 0) ? vul[r - 1] : 0u) |
                             ((r < WW - 1) ? vul[r + 1] : 0u) |
                             ((vul[r] << 1) & M19) | (vul[r] >> 1);
        uint32_t leg = e[r] & (u | d | ((e[r] << 1) & M19) | (e[r] >> 1));
        leg |= e[r] & nbv;
        if (kk.x == r) leg &= ~(1u << kk.y);
        pb[57 + r] = leg;
      }

      // Flood: Gauss-Seidel down/up sweeps of scanline runfill (in-place, no
      // ex[]/rm[] arrays -> fits registers).
      uint32_t g[WW];
#pragma unroll
      for (int r = 0; r < WW; ++r) g[r] = runfill(vul[r], m[r]);
      for (int it = 0; it < 45; ++it) {
        uint32_t chg = 0, prev = 0;
#pragma unroll
        for (int r = 0; r < WW; ++r) {
          uint32_t t = g[r] | (prev & m[r]);
          t = runfill(t, m[r]);
          chg |= t ^ g[r];
          g[r] = t;
          prev = t;
        }
        prev = 0;
#pragma unroll
        for (int r = WW - 1; r >= 0; --r) {
          uint32_t t = g[r] | (prev & m[r]);
          t = runfill(t, m[r]);
          chg |= t ^ g[r];
          g[r] = t;
          prev = t;
        }
        if (!__any(chg != 0u)) break;
      }
#pragma unroll
      for (int r = 0; r < WW; ++r) pb[76 + r] = g[r];
    }
  }
  __syncthreads();

  // ---------------- phase 3: expand LDS row-planes -> float4 outputs --------
  if (b0 + BPB <= B) {
    // Block's 16 boards are contiguous; 16*361*4B chunks are 16B-aligned.
    float4* s0 = (float4*)(out + (size_t)b0 * NP);
    float4* s1 = (float4*)(out + NB + (size_t)b0 * NP);
    float4* s2 = (float4*)(out + 2 * NB + (size_t)b0 * NP);
    const int nq = BPB * NP / 4;  // 1444
    for (int q = threadIdx.x; q < nq; q += TPB) {
      float t0[4], t1[4], t2[4];
#pragma unroll
      for (int j = 0; j < 4; ++j) {
        const int id = q * 4 + j;
        const int lb = (id * 92949) >> 25;      // id/361 for id<5776
        const int p = id - lb * NP;
        const int r = (p * 27) >> 9;            // p/19 for p<512
        const int c = p - r * WW;
        const uint32_t* pb = &pl[lb * PLSTR];
        const uint32_t l0 = (pb[r] >> c) & 1u;
        const uint32_t l1 = (pb[19 + r] >> c) & 1u;
        const uint32_t l2 = (pb[38 + r] >> c) & 1u;
        t0[j] = (float)(l0 + 2u * l1 + 4u * l2);
        t1[j] = (float)((pb[57 + r] >> c) & 1u);
        t2[j] = (float)((pb[76 + r] >> c) & 1u);
      }
      s0[q] = make_float4(t0[0], t0[1], t0[2], t0[3]);
      s1[q] = make_float4(t1[0], t1[1], t1[2], t1[3]);
      s2[q] = make_float4(t2[0], t2[1], t2[2], t2[3]);
    }
  } else {
    // Tail block: scalar per-board path.
#pragma unroll
    for (int k = 0; k < 4; ++k) {
      const int lb = wid * 4 + k;
      const int b = b0 + lb;
      if (b < B) {
        float* o0 = out + (size_t)b * NP;
        const uint32_t* pb = &pl[lb * PLSTR];
#pragma unroll
        for (int i = 0; i < 6; ++i) {
          const int p = i * 64 + lane;
          if (p < NP) {
            const int r = (p * 27) >> 9;
            const int c = p - r * WW;
            const uint32_t l0 = (pb[r] >> c) & 1u;
            const uint32_t l1 = (pb[19 + r] >> c) & 1u;
            const uint32_t l2 = (pb[38 + r] >> c) & 1u;
            o0[p] = (float)(l0 + 2u * l1 + 4u * l2);
            o0[NB + p] = (float)((pb[57 + r] >> c) & 1u);
            o0[2 * NB + p] = (float)((pb[76 + r] >> c) & 1u);
          }
        }
      }
    }
  }
}

extern "C" void kernel_launch(void* const* d_in, const int* in_sizes, int n_in,
                              void* d_out, int out_size, void* d_ws,
                              size_t ws_size, hipStream_t stream) {
  const float* stones = (const float*)d_in[0];
  const int* cur = (const int*)d_in[1];
  const int* ko = (const int*)d_in[2];
  const int* zob = (const int*)d_in[3];
  const int* zturn = (const int*)d_in[4];
  const int* phash = (const int*)d_in[5];
  float* out = (float*)d_out;

  const int B = in_sizes[0] / (2 * NP);
  const int blocks = (B + BPB - 1) / BPB;
  go_fused<<<blocks, TPB, 0, stream>>>(stones, cur, ko, zob, zturn, phash, out,
                                       B);
}

// Round 6
// 29.755 us; speedup vs baseline: 1.3817x; 1.1005x over previous
//
#include <hip/hip_runtime.h>
#include <stdint.h>

#define WW 19
#define NP 361
#define M19 0x7FFFFu
#define BPW 3                 // boards per wave (3*19 = 57 active lanes)
#define NWAVES 4
#define BPB (BPW * NWAVES)    // 12 boards per block
#define TPB 256
#define BBSTR 25              // u32 stride for packed bitboards in LDS
#define PLSTR 97              // u32 stride for row-planes in LDS

__device__ __forceinline__ uint32_t rev19(uint32_t x) { return __brev(x) >> 13; }

// Fill every horizontal run of m containing a seed of g (g subset of m).
__device__ __forceinline__ uint32_t runfill(uint32_t g, uint32_t m) {
  const uint32_t up = g | (m & ((m + g) ^ m ^ g));
  const uint32_t rm = rev19(m);
  const uint32_t rg = rev19(g);
  const uint32_t dn = rg | (rm & ((rm + rg) ^ rm ^ rg));
  return up | rev19(dn);
}

__global__ __launch_bounds__(TPB, 4) void go_fused(
    const float* __restrict__ stones, const int* __restrict__ cur,
    const int* __restrict__ ko, const int* __restrict__ zob,
    const int* __restrict__ zturn, const int* __restrict__ phash,
    float* __restrict__ out, int B) {
  __shared__ uint32_t bbuf[BPB * BBSTR];
  __shared__ uint32_t pl[BPB * PLSTR];

  const int wid = threadIdx.x >> 6;
  const int lane = threadIdx.x & 63;
  const int b0 = blockIdx.x * BPB;
  const size_t NB = (size_t)B * NP;

  // Zobrist tables: uniform across blocks, L1/L2-cached.
  int zb[6], zw[6];
#pragma unroll
  for (int i = 0; i < 6; ++i) {
    const int p = i * 64 + lane;
    zb[i] = (p < NP) ? zob[p] : 0;
    zw[i] = (p < NP) ? zob[NP + p] : 0;
  }
  const int zt = zturn[0] ^ zturn[1];

  // ---------------- phase 1: pack stones -> LDS bitboards, zobrist hash -----
  int acc[BPW];
#pragma unroll
  for (int k = 0; k < BPW; ++k) {
    const int lb = wid * BPW + k;
    const int b = b0 + lb;
    acc[k] = 0;
    if (b < B) {
      const float* sb = stones + (size_t)b * (2 * NP);
#pragma unroll
      for (int i = 0; i < 6; ++i) {
        const int p = i * 64 + lane;
        const bool inb = p < NP;
        const float bv = inb ? sb[p] : 0.0f;
        const float wv = inb ? sb[NP + p] : 0.0f;
        const bool bs = bv > 0.5f, wsn = wv > 0.5f;
        const uint64_t bbm = __ballot(bs);
        const uint64_t wbm = __ballot(wsn);
        if (lane < 4) {
          const uint64_t src = (lane < 2) ? bbm : wbm;
          const uint32_t vv = (lane & 1) ? (uint32_t)(src >> 32) : (uint32_t)src;
          bbuf[lb * BBSTR + i * 4 + lane] = vv;
        }
        acc[k] ^= zb[i] & (bs ? -1 : 0);
        acc[k] ^= zw[i] & (wsn ? -1 : 0);
      }
    }
  }
#pragma unroll
  for (int off = 32; off > 0; off >>= 1) {
#pragma unroll
    for (int k = 0; k < BPW; ++k) acc[k] ^= __shfl_xor(acc[k], off, 64);
  }
  if (lane == 0) {
#pragma unroll
    for (int k = 0; k < BPW; ++k) {
      const int b = b0 + wid * BPW + k;
      if (b < B) out[3 * NB + b] = (float)(phash[b] ^ acc[k] ^ zt);
    }
  }
  __syncthreads();

  // ---------------- phase 2: row-per-lane, 3 boards per wave -----------------
  {
    const int k = (lane * 27) >> 9;  // lane / 19
    const int r = lane - k * WW;
    const int lb = wid * BPW + k;
    const int b = b0 + lb;
    const bool vl = (lane < 57) && (b < B);
    const int lbs = vl ? lb : 0;
    const int bsafe = vl ? b : (B - 1);

    const int cp = cur[bsafe];
    const int2 kk = ((const int2*)ko)[bsafe];

    // Extract this lane's row (19 bits) of black/white from packed bitboards.
    uint32_t mrow, erow;
    {
      const int bit = WW * r;
      const int w = bit >> 6, sh = bit & 63;
      const uint32_t* q = &bbuf[lbs * BBSTR + 4 * w];
      const uint64_t Blo = (uint64_t)q[0] | ((uint64_t)q[1] << 32);
      const uint64_t Wlo = (uint64_t)q[2] | ((uint64_t)q[3] << 32);
      uint32_t br = (uint32_t)(Blo >> sh);
      uint32_t wr = (uint32_t)(Wlo >> sh);
      if (sh > 45) {  // row straddles a 64-bit word boundary
        const uint64_t Bhi = (uint64_t)q[4] | ((uint64_t)q[5] << 32);
        const uint64_t Whi = (uint64_t)q[6] | ((uint64_t)q[7] << 32);
        br |= (uint32_t)(Bhi << (64 - sh));
        wr |= (uint32_t)(Whi << (64 - sh));
      }
      br &= M19;
      wr &= M19;
      mrow = vl ? ((cp == 0) ? wr : br) : 0u;
      erow = vl ? (~(br | wr) & M19) : 0u;
    }

    // Liberties / legal / vulnerable (vertical neighbors via shfl).
    uint32_t t;
    t = __shfl(erow, lane - 1, 64);
    const uint32_t eu = (r > 0) ? t : 0u;
    t = __shfl(erow, lane + 1, 64);
    const uint32_t ed = (r < 18) ? t : 0u;
    const uint32_t el = (erow << 1) & M19;
    const uint32_t er_ = erow >> 1;
    const uint32_t s1 = eu ^ ed, c1 = eu & ed;
    const uint32_t s2 = el ^ er_, c2 = el & er_;
    const uint32_t cc = s1 & s2;
    const uint32_t L0 = s1 ^ s2;
    const uint32_t L1 = c1 ^ c2 ^ cc;
    const uint32_t L2 = (c1 & c2) | (cc & (c1 | c2));
    uint32_t leg = erow & (eu | ed | el | er_);
    const uint32_t vul = mrow & L0 & ~L1;  // liberty count == 1
    t = __shfl(vul, lane - 1, 64);
    const uint32_t vu = (r > 0) ? t : 0u;
    t = __shfl(vul, lane + 1, 64);
    const uint32_t vd = (r < 18) ? t : 0u;
    leg |= erow & (vu | vd | ((vul << 1) & M19) | (vul >> 1));
    if (kk.x == r) leg &= ~(1u << kk.y);

    // Flood fill: horizontal runfill + vertical shfl step, early exit.
    uint32_t g = runfill(vul, mrow);
    for (int it = 0; it < 90; ++it) {
      t = __shfl(g, lane - 1, 64);
      const uint32_t gu = (r > 0) ? t : 0u;
      t = __shfl(g, lane + 1, 64);
      const uint32_t gd = (r < 18) ? t : 0u;
      const uint32_t gn = runfill(g | ((gu | gd) & mrow), mrow);
      if (!__any(gn != g)) break;
      g = gn;
    }

    if (vl) {
      uint32_t* pb = &pl[lb * PLSTR];
      pb[r] = L0;
      pb[19 + r] = L1;
      pb[38 + r] = L2;
      pb[57 + r] = leg;
      pb[76 + r] = g;
    }
  }
  __syncthreads();

  // ---------------- phase 3: expand LDS row-planes -> float4 outputs --------
  if (b0 + BPB <= B) {
    float4* s0 = (float4*)(out + (size_t)b0 * NP);
    float4* s1 = (float4*)(out + NB + (size_t)b0 * NP);
    float4* s2 = (float4*)(out + 2 * NB + (size_t)b0 * NP);
    const int nq = BPB * NP / 4;  // 1083
    for (int q = threadIdx.x; q < nq; q += TPB) {
      float t0[4], t1[4], t2[4];
#pragma unroll
      for (int j = 0; j < 4; ++j) {
        const int id = q * 4 + j;
        const int lb = (id * 92949) >> 25;  // id/361 for id<5776
        const int p = id - lb * NP;
        const int r = (p * 27) >> 9;        // p/19 for p<512
        const int c = p - r * WW;
        const uint32_t* pb = &pl[lb * PLSTR];
        const uint32_t l0 = (pb[r] >> c) & 1u;
        const uint32_t l1 = (pb[19 + r] >> c) & 1u;
        const uint32_t l2 = (pb[38 + r] >> c) & 1u;
        t0[j] = (float)(l0 + 2u * l1 + 4u * l2);
        t1[j] = (float)((pb[57 + r] >> c) & 1u);
        t2[j] = (float)((pb[76 + r] >> c) & 1u);
      }
      s0[q] = make_float4(t0[0], t0[1], t0[2], t0[3]);
      s1[q] = make_float4(t1[0], t1[1], t1[2], t1[3]);
      s2[q] = make_float4(t2[0], t2[1], t2[2], t2[3]);
    }
  } else {
    // Tail block: scalar per-board path.
#pragma unroll
    for (int k = 0; k < BPW; ++k) {
      const int lb = wid * BPW + k;
      const int b = b0 + lb;
      if (b < B) {
        float* o0 = out + (size_t)b * NP;
        const uint32_t* pb = &pl[lb * PLSTR];
#pragma unroll
        for (int i = 0; i < 6; ++i) {
          const int p = i * 64 + lane;
          if (p < NP) {
            const int r = (p * 27) >> 9;
            const int c = p - r * WW;
            const uint32_t l0 = (pb[r] >> c) & 1u;
            const uint32_t l1 = (pb[19 + r] >> c) & 1u;
            const uint32_t l2 = (pb[38 + r] >> c) & 1u;
            o0[p] = (float)(l0 + 2u * l1 + 4u * l2);
            o0[NB + p] = (float)((pb[57 + r] >> c) & 1u);
            o0[2 * NB + p] = (float)((pb[76 + r] >> c) & 1u);
          }
        }
      }
    }
  }
}

extern "C" void kernel_launch(void* const* d_in, const int* in_sizes, int n_in,
                              void* d_out, int out_size, void* d_ws,
                              size_t ws_size, hipStream_t stream) {
  const float* stones = (const float*)d_in[0];
  const int* cur = (const int*)d_in[1];
  const int* ko = (const int*)d_in[2];
  const int* zob = (const int*)d_in[3];
  const int* zturn = (const int*)d_in[4];
  const int* phash = (const int*)d_in[5];
  float* out = (float*)d_out;

  const int B = in_sizes[0] / (2 * NP);
  const int blocks = (B + BPB - 1) / BPB;
  go_fused<<<blocks, TPB, 0, stream>>>(stones, cur, ko, zob, zturn, phash, out,
                                       B);
}

// Round 7
// 29.586 us; speedup vs baseline: 1.3895x; 1.0057x over previous
//
#include <hip/hip_runtime.h>
#include <stdint.h>

#define WW 19
#define NP 361
#define M19 0x7FFFFu
#define BPW 3                  // boards per wave in row phase (3*19 = 57 lanes)
#define NWAVES 8
#define BPB 24                 // boards per block (8 waves * 3)
#define TPB 512
#define CHF (BPB * 722)        // 17328 floats per full stone chunk
#define CH4 (CHF / 4)          // 4332 float4s
#define BMW 548                // bitmap dwords (17328/32 = 541.5 -> 542, padded)
#define PLSTR 97               // u32 stride for row-planes in LDS

typedef float f32x4 __attribute__((ext_vector_type(4)));

__device__ __forceinline__ uint32_t rev19(uint32_t x) { return __brev(x) >> 13; }

// Fill every horizontal run of m containing a seed of g (g subset of m).
__device__ __forceinline__ uint32_t runfill(uint32_t g, uint32_t m) {
  const uint32_t up = g | (m & ((m + g) ^ m ^ g));
  const uint32_t rm = rev19(m);
  const uint32_t rg = rev19(g);
  const uint32_t dn = rg | (rm & ((rm + rg) ^ rm ^ rg));
  return up | rev19(dn);
}

__global__ __launch_bounds__(TPB, 2) void go_fused(
    const float* __restrict__ stones, const int* __restrict__ cur,
    const int* __restrict__ ko, const int* __restrict__ zob,
    const int* __restrict__ zturn, const int* __restrict__ phash,
    float* __restrict__ out, int B) {
  __shared__ uint32_t bmp[BMW];          // linear stone bitmap: cell i = bit i
  __shared__ uint32_t pl[BPB * PLSTR];   // row planes: L0,L1,L2,legal,groups

  const int wid = threadIdx.x >> 6;
  const int lane = threadIdx.x & 63;
  const int b0 = blockIdx.x * BPB;
  const int nb = min(BPB, B - b0);
  const size_t NB = (size_t)B * NP;

  // Zero bitmap.
  for (int t = threadIdx.x; t < BMW; t += TPB) bmp[t] = 0;

  // Zobrist tables preloaded into registers (uniform across blocks, cached).
  int zb[6], zw[6];
#pragma unroll
  for (int i = 0; i < 6; ++i) {
    const int p = i * 64 + lane;
    zb[i] = (p < NP) ? zob[p] : 0;
    zw[i] = (p < NP) ? zob[NP + p] : 0;
  }
  const int zt = zturn[0] ^ zturn[1];
  __syncthreads();

  // ---------------- phase 1: float4 loads -> bit nibbles -> LDS bitmap ------
  {
    const f32x4* src = (const f32x4*)(stones + (size_t)b0 * 722);
    const int nf4 = nb * 722 / 4;  // nb is even for all real tails
#pragma unroll
    for (int j = 0; j < (CH4 + TPB - 1) / TPB; ++j) {
      const int q = threadIdx.x + TPB * j;
      uint32_t m = 0;
      if (q < nf4) {
        const f32x4 v = __builtin_nontemporal_load(&src[q]);
        m = (uint32_t)(v.x > 0.5f) | ((uint32_t)(v.y > 0.5f) << 1) |
            ((uint32_t)(v.z > 0.5f) << 2) | ((uint32_t)(v.w > 0.5f) << 3);
      }
      // Butterfly combine 8 consecutive threads' nibbles into one dword.
      uint32_t x = m | ((uint32_t)__shfl_xor((int)m, 1, 64) << 4);
      x = x | ((uint32_t)__shfl_xor((int)x, 2, 64) << 8);
      x = x | ((uint32_t)__shfl_xor((int)x, 4, 64) << 16);
      if ((lane & 7) == 0 && q < CH4) bmp[q >> 3] = x;
    }
  }
  __syncthreads();

  // ---------------- phase 1.5: zobrist hash from bitmap (wave per 3 boards) -
  {
    int hv[BPW];
#pragma unroll
    for (int k = 0; k < BPW; ++k) {
      const int lb = wid * BPW + k;
      const uint32_t base = lb * 722;
      int h = 0;
#pragma unroll
      for (int i = 0; i < 6; ++i) {
        const int cc = i * 64 + lane;
        if (cc < NP) {
          uint32_t pos = base + cc;
          uint32_t s = (bmp[pos >> 5] >> (pos & 31)) & 1u;
          h ^= zb[i] & -(int)s;
          pos = base + 361 + cc;
          s = (bmp[pos >> 5] >> (pos & 31)) & 1u;
          h ^= zw[i] & -(int)s;
        }
      }
      hv[k] = h;
    }
#pragma unroll
    for (int off = 32; off > 0; off >>= 1) {
#pragma unroll
      for (int k = 0; k < BPW; ++k) hv[k] ^= __shfl_xor(hv[k], off, 64);
    }
    if (lane == 0) {
#pragma unroll
      for (int k = 0; k < BPW; ++k) {
        const int b = b0 + wid * BPW + k;
        if (b < B) out[3 * NB + b] = (float)(phash[b] ^ hv[k] ^ zt);
      }
    }
  }

  // ---------------- phase 2: row-per-lane bitboard algebra + flood ----------
  {
    const int k = (lane * 27) >> 9;  // lane / 19
    const int r = lane - k * WW;
    const int lb = wid * BPW + k;
    const int b = b0 + lb;
    const bool vl = (lane < 57) && (lb < nb);
    const int lbs = vl ? lb : 0;

    // Extract this lane's black/white rows from the bitmap (funnel shift).
    uint32_t brow, wrow;
    {
      const uint32_t base = (uint32_t)lbs * 722 + (uint32_t)r * WW;
      const uint32_t d = base >> 5, sh = base & 31;
      const uint64_t w = ((uint64_t)bmp[d + 1] << 32) | bmp[d];
      brow = (uint32_t)(w >> sh) & M19;
      const uint32_t base2 = base + 361;
      const uint32_t d2 = base2 >> 5, sh2 = base2 & 31;
      const uint64_t w2 = ((uint64_t)bmp[d2 + 1] << 32) | bmp[d2];
      wrow = (uint32_t)(w2 >> sh2) & M19;
    }
    const int cp = vl ? cur[b] : 0;
    int2 kk = {-1, -1};
    if (vl) kk = ((const int2*)ko)[b];
    uint32_t mrow = (cp == 0) ? wrow : brow;
    uint32_t erow = ~(brow | wrow) & M19;
    if (!vl) { mrow = 0; erow = 0; }

    // Liberties / legal / vulnerable (vertical neighbors via shfl).
    uint32_t t;
    t = __shfl(erow, lane - 1, 64);
    const uint32_t eu = (r > 0) ? t : 0u;
    t = __shfl(erow, lane + 1, 64);
    const uint32_t ed = (r < 18) ? t : 0u;
    const uint32_t el = (erow << 1) & M19;
    const uint32_t er_ = erow >> 1;
    const uint32_t s1 = eu ^ ed, c1 = eu & ed;
    const uint32_t s2 = el ^ er_, c2 = el & er_;
    const uint32_t cc = s1 & s2;
    const uint32_t L0 = s1 ^ s2;
    const uint32_t L1 = c1 ^ c2 ^ cc;
    const uint32_t L2 = (c1 & c2) | (cc & (c1 | c2));
    uint32_t leg = erow & (eu | ed | el | er_);
    const uint32_t vul = mrow & L0 & ~L1;  // liberty count == 1
    t = __shfl(vul, lane - 1, 64);
    const uint32_t vu = (r > 0) ? t : 0u;
    t = __shfl(vul, lane + 1, 64);
    const uint32_t vd = (r < 18) ? t : 0u;
    leg |= erow & (vu | vd | ((vul << 1) & M19) | (vul >> 1));
    if (kk.x == r) leg &= ~(1u << kk.y);

    // Flood fill: horizontal runfill + vertical shfl step, early exit.
    uint32_t g = runfill(vul, mrow);
    for (int it = 0; it < 90; ++it) {
      t = __shfl(g, lane - 1, 64);
      const uint32_t gu = (r > 0) ? t : 0u;
      t = __shfl(g, lane + 1, 64);
      const uint32_t gd = (r < 18) ? t : 0u;
      const uint32_t gn = runfill(g | ((gu | gd) & mrow), mrow);
      if (!__any(gn != g)) break;
      g = gn;
    }

    if (vl) {
      uint32_t* pb = &pl[lb * PLSTR];
      pb[r] = L0;
      pb[19 + r] = L1;
      pb[38 + r] = L2;
      pb[57 + r] = leg;
      pb[76 + r] = g;
    }
  }
  __syncthreads();

  // ---------------- phase 3: expand LDS row-planes -> float4 nt stores ------
  {
    const int nq = nb * NP / 4;  // exact when nb % 4 == 0 (24 and 16 tails)
    f32x4* s0 = (f32x4*)(out + (size_t)b0 * NP);
    f32x4* s1 = (f32x4*)(out + NB + (size_t)b0 * NP);
    f32x4* s2 = (f32x4*)(out + 2 * NB + (size_t)b0 * NP);
    for (int q = threadIdx.x; q < nq; q += TPB) {
      f32x4 t0, t1, t2;
#pragma unroll
      for (int j = 0; j < 4; ++j) {
        const int id = q * 4 + j;
        const int lb = (int)(((uint64_t)id * 5948986ull) >> 31);  // id/361
        const int p = id - lb * NP;
        const int r = (p * 27) >> 9;  // p/19 for p<512
        const int c = p - r * WW;
        const uint32_t* pb = &pl[lb * PLSTR];
        const uint32_t l0 = (pb[r] >> c) & 1u;
        const uint32_t l1 = (pb[19 + r] >> c) & 1u;
        const uint32_t l2 = (pb[38 + r] >> c) & 1u;
        t0[j] = (float)(l0 + 2u * l1 + 4u * l2);
        t1[j] = (float)((pb[57 + r] >> c) & 1u);
        t2[j] = (float)((pb[76 + r] >> c) & 1u);
      }
      __builtin_nontemporal_store(t0, &s0[q]);
      __builtin_nontemporal_store(t1, &s1[q]);
      __builtin_nontemporal_store(t2, &s2[q]);
    }
    // Generic remainder guard (unused for B=16384, kept for safety).
    const int rem0 = nq * 4;
    for (int id = rem0 + threadIdx.x; id < nb * NP; id += TPB) {
      const int lb = (int)(((uint64_t)id * 5948986ull) >> 31);
      const int p = id - lb * NP;
      const int r = (p * 27) >> 9;
      const int c = p - r * WW;
      const uint32_t* pb = &pl[lb * PLSTR];
      const uint32_t l0 = (pb[r] >> c) & 1u;
      const uint32_t l1 = (pb[19 + r] >> c) & 1u;
      const uint32_t l2 = (pb[38 + r] >> c) & 1u;
      out[(size_t)b0 * NP + id] = (float)(l0 + 2u * l1 + 4u * l2);
      out[NB + (size_t)b0 * NP + id] = (float)((pb[57 + r] >> c) & 1u);
      out[2 * NB + (size_t)b0 * NP + id] = (float)((pb[76 + r] >> c) & 1u);
    }
  }
}

extern "C" void kernel_launch(void* const* d_in, const int* in_sizes, int n_in,
                              void* d_out, int out_size, void* d_ws,
                              size_t ws_size, hipStream_t stream) {
  const float* stones = (const float*)d_in[0];
  const int* cur = (const int*)d_in[1];
  const int* ko = (const int*)d_in[2];
  const int* zob = (const int*)d_in[3];
  const int* zturn = (const int*)d_in[4];
  const int* phash = (const int*)d_in[5];
  float* out = (float*)d_out;

  const int B = in_sizes[0] / (2 * NP);
  const int blocks = (B + BPB - 1) / BPB;
  go_fused<<<blocks, TPB, 0, stream>>>(stones, cur, ko, zob, zturn, phash, out,
                                       B);
}